// Round 1
// baseline (439.287 us; speedup 1.0000x reference)
//
#include <hip/hip_runtime.h>
#include <hip/hip_bf16.h>

namespace {

constexpr int S_LEN = 2048;
constexpr int DH    = 128;
constexpr int QBLK  = 64;   // q rows per block (4 waves x 16)
constexpr int KVB   = 32;   // kv rows per tile
constexpr int NW    = 4;

typedef __attribute__((ext_vector_type(8))) short   short8;
typedef __attribute__((ext_vector_type(8))) __bf16  bf16x8;
typedef __attribute__((ext_vector_type(4))) float   f32x4;

__device__ __forceinline__ short f2bf(float x) {
    __hip_bfloat16 h = __float2bfloat16(x);
    return __builtin_bit_cast(short, h);
}
__device__ __forceinline__ unsigned pk2(float a, float b) {
    return (unsigned)(unsigned short)f2bf(a) | ((unsigned)(unsigned short)f2bf(b) << 16);
}
__device__ __forceinline__ f32x4 mfma16(short8 a, short8 b, f32x4 c) {
    return __builtin_amdgcn_mfma_f32_16x16x32_bf16(
        __builtin_bit_cast(bf16x8, a), __builtin_bit_cast(bf16x8, b), c, 0, 0, 0);
}

__global__ void __launch_bounds__(256)
attn_fwd(const float* __restrict__ Qp, const float* __restrict__ Kp,
         const float* __restrict__ Vp, float* __restrict__ Op)
{
    __shared__ __align__(16) short ksm[KVB * DH];       // K tile, row-major, XOR-swizzled
    __shared__ __align__(16) short vtm[DH * KVB];       // V^T tile, XOR-swizzled
    __shared__ __align__(16) short pbf[NW * 16 * KVB];  // per-wave P transpose buffer

    const int qb   = (int)gridDim.x - 1 - (int)blockIdx.x;  // heavy blocks first
    const int bh   = blockIdx.y;
    const int tid  = threadIdx.x;
    const int w    = tid >> 6;
    const int lane = tid & 63;
    const int m    = lane & 15;
    const int g    = lane >> 4;

    const size_t base = (size_t)bh * (S_LEN * DH);
    const int q0 = qb * QBLK;
    const int qw = q0 + 16 * w;                // this wave's first q row

    const float QS = 0.08838834764831845f * 1.4426950408889634f; // 1/sqrt(128) * log2(e)

    // ---- Q fragments to registers (A-layout: row = m, k = 8g + j + 32t) ----
    short8 qa[4];
    {
        const float* qrow = Qp + base + (size_t)(qw + m) * DH + 8 * g;
        #pragma unroll
        for (int t = 0; t < 4; ++t) {
            f32x4 f0 = *reinterpret_cast<const f32x4*>(qrow + 32 * t);
            f32x4 f1 = *reinterpret_cast<const f32x4*>(qrow + 32 * t + 4);
            short8 a;
            a[0] = f2bf(f0[0] * QS); a[1] = f2bf(f0[1] * QS);
            a[2] = f2bf(f0[2] * QS); a[3] = f2bf(f0[3] * QS);
            a[4] = f2bf(f1[0] * QS); a[5] = f2bf(f1[1] * QS);
            a[6] = f2bf(f1[2] * QS); a[7] = f2bf(f1[3] * QS);
            qa[t] = a;
        }
    }

    f32x4 o[8];
    #pragma unroll
    for (int i = 0; i < 8; ++i) o[i] = (f32x4){0.f, 0.f, 0.f, 0.f};
    float mrow[4] = {-1e30f, -1e30f, -1e30f, -1e30f};
    float lrow[4] = {0.f, 0.f, 0.f, 0.f};

    const int nkt = (q0 + QBLK) / KVB;
    const int skr = tid >> 3;            // K staging: row 0..31
    const int skd = (tid & 7) * 4;       // K staging: d base
    const int svd = tid >> 1;            // V staging: d 0..127
    const int svk = (tid & 1) * 16;      // V staging: k base

    for (int kt = 0; kt < nkt; ++kt) {
        const int k0 = kt * KVB;
        __syncthreads();
        // ---- stage K (fp32 -> bf16, row-major, swizzle byte^((row&15)<<4)) ----
        {
            const float* krow = Kp + base + (size_t)(k0 + skr) * DH;
            #pragma unroll
            for (int i = 0; i < 4; ++i) {
                const int d = skd + 32 * i;
                f32x4 f = *reinterpret_cast<const f32x4*>(krow + d);
                uint2 u;
                u.x = pk2(f[0], f[1]);
                u.y = pk2(f[2], f[3]);
                const int e = (skr * DH + d) ^ ((skr & 15) << 3);
                *reinterpret_cast<uint2*>(&ksm[e]) = u;
            }
        }
        // ---- stage V^T (column gather, pack 16 k per d-row, swizzled) ----
        {
            const float* vcol = Vp + base + (size_t)(k0 + svk) * DH + svd;
            short tmp[16];
            #pragma unroll
            for (int j = 0; j < 16; ++j) tmp[j] = f2bf(vcol[(size_t)j * DH]);
            #pragma unroll
            for (int c = 0; c < 2; ++c) {
                short8 s8;
                #pragma unroll
                for (int j = 0; j < 8; ++j) s8[j] = tmp[8 * c + j];
                const int e = (svd * KVB + svk + 8 * c) ^ ((svd & 7) << 3);
                *reinterpret_cast<short8*>(&vtm[e]) = s8;
            }
        }
        __syncthreads();

        if (k0 <= qw + 15) {   // tile not fully masked for this wave
            // ---- QK^T: S[16 q x 32 k], accumulate over d ----
            f32x4 sc[2];
            sc[0] = (f32x4){0.f, 0.f, 0.f, 0.f};
            sc[1] = (f32x4){0.f, 0.f, 0.f, 0.f};
            #pragma unroll
            for (int c = 0; c < 2; ++c) {
                const int row = 16 * c + m;
                #pragma unroll
                for (int t = 0; t < 4; ++t) {
                    const int e = (row * DH + 32 * t + 8 * g) ^ ((row & 15) << 3);
                    short8 kb = *reinterpret_cast<const short8*>(&ksm[e]);
                    sc[c] = mfma16(qa[t], kb, sc[c]);
                }
            }
            // ---- causal mask (only when tile crosses the diagonal) ----
            if (k0 + KVB - 1 > qw) {
                #pragma unroll
                for (int c = 0; c < 2; ++c) {
                    const int kcol = k0 + 16 * c + m;
                    #pragma unroll
                    for (int r = 0; r < 4; ++r) {
                        if (kcol > qw + 4 * g + r) sc[c][r] = -1e30f;
                    }
                }
            }
            // ---- online softmax (exp2 domain; rows live on fixed 16-lane groups) ----
            float p0[4], p1[4], alpha[4];
            #pragma unroll
            for (int r = 0; r < 4; ++r) {
                float rm = fmaxf(sc[0][r], sc[1][r]);
                rm = fmaxf(rm, __shfl_xor(rm, 1));
                rm = fmaxf(rm, __shfl_xor(rm, 2));
                rm = fmaxf(rm, __shfl_xor(rm, 4));
                rm = fmaxf(rm, __shfl_xor(rm, 8));
                const float mn = fmaxf(mrow[r], rm);
                alpha[r] = exp2f(mrow[r] - mn);
                mrow[r]  = mn;
                p0[r] = exp2f(sc[0][r] - mn);
                p1[r] = exp2f(sc[1][r] - mn);
                float rs = p0[r] + p1[r];
                rs += __shfl_xor(rs, 1);
                rs += __shfl_xor(rs, 2);
                rs += __shfl_xor(rs, 4);
                rs += __shfl_xor(rs, 8);
                lrow[r] = lrow[r] * alpha[r] + rs;
            }
            #pragma unroll
            for (int i = 0; i < 8; ++i) {
                o[i][0] *= alpha[0]; o[i][1] *= alpha[1];
                o[i][2] *= alpha[2]; o[i][3] *= alpha[3];
            }
            // ---- P -> per-wave LDS (transpose to A-layout) ----
            short* pw = &pbf[w * (16 * KVB)];
            #pragma unroll
            for (int r = 0; r < 4; ++r) {
                const int q  = 4 * g + r;
                const int eb = q * KVB;
                const int sw = (q & 7) << 3;
                pw[(eb + m) ^ sw]      = f2bf(p0[r]);
                pw[(eb + 16 + m) ^ sw] = f2bf(p1[r]);
            }
            asm volatile("s_waitcnt lgkmcnt(0)" ::: "memory");
            const int ep = (m * KVB + 8 * g) ^ ((m & 7) << 3);
            short8 pa = *reinterpret_cast<const short8*>(&pw[ep]);
            // ---- PV: O[16 q x 128 d] += P x V ----
            #pragma unroll
            for (int db = 0; db < 8; ++db) {
                const int drow = 16 * db + m;
                const int ev = (drow * KVB + 8 * g) ^ ((drow & 7) << 3);
                short8 vb = *reinterpret_cast<const short8*>(&vtm[ev]);
                o[db] = mfma16(pa, vb, o[db]);
            }
        }
    }

    // ---- epilogue: normalize and store ----
    float rl[4];
    #pragma unroll
    for (int r = 0; r < 4; ++r) rl[r] = 1.0f / lrow[r];
    #pragma unroll
    for (int db = 0; db < 8; ++db) {
        #pragma unroll
        for (int r = 0; r < 4; ++r) {
            Op[base + (size_t)(qw + 4 * g + r) * DH + 16 * db + m] = o[db][r] * rl[r];
        }
    }
}

} // namespace

extern "C" void kernel_launch(void* const* d_in, const int* in_sizes, int n_in,
                              void* d_out, int out_size, void* d_ws, size_t ws_size,
                              hipStream_t stream)
{
    const float* Q = (const float*)d_in[0];
    const float* K = (const float*)d_in[1];
    const float* V = (const float*)d_in[2];
    float* O = (float*)d_out;
    dim3 grid(S_LEN / QBLK, 32);   // x: q-blocks (reversed inside), y: b*h
    dim3 block(256);
    hipLaunchKernelGGL(attn_fwd, grid, block, 0, stream, Q, K, V, O);
}